// Round 2
// baseline (862.297 us; speedup 1.0000x reference)
//
#include <hip/hip_runtime.h>
#include <math.h>

// ---- static problem structure -------------------------------------------
// Inputs (dict order!): A0, B0, A1, B1, A2, B2, A3, B3 : [4096, 2l+1, 16] f32.
// Packed per-batch layout (256 floats): row offsets loff = {0,16,64,144},
// element (l, m_i, p) at loff[l] + m_i*16 + p.
// Output per batch: for l=0..3, for M, for pair (l1,l2) valid, 256-elt tile
// (p*16+q). Tile base = base[l] + (M*npairs[l] + pair)*256.
// base = {0,1024,7936,22016}, npairs = {4,9,11,10}. Total 39936 f32/batch.
#define NTILES 156
#define NTERMS 478
#define PB_OUT 39936

__device__ double factd(int n){ double f=1.0; for(int i=2;i<=n;++i) f*=(double)i; return f; }

__device__ double cg_scalar(int j1,int m1,int j2,int m2,int j,int m){
  if (m1+m2 != m) return 0.0;
  double pref = sqrt((2.0*j+1.0)*factd(j+j1-j2)*factd(j-j1+j2)*factd(j1+j2-j)/factd(j1+j2+j+1));
  pref *= sqrt(factd(j+m)*factd(j-m)*factd(j1+m1)*factd(j1-m1)*factd(j2+m2)*factd(j2-m2));
  double s=0.0;
  for(int k=0;k<=j1+j2-j;++k){
    int d2=j1+j2-j-k, d3=j1-m1-k, d4=j2+m2-k, d5=j-j2+m1+k, d6=j-j1-m2+k;
    if(d2<0||d3<0||d4<0||d5<0||d6<0) continue;
    double denom = factd(k)*factd(d2)*factd(d3)*factd(d4)*factd(d5)*factd(d6);
    s += ((k&1)? -1.0:1.0)/denom;
  }
  return pref*s;
}

// Builds: tiles[156]  : out_off | (term_start<<16) | (count<<26)
//         tpack[478]  : a_off | (b_off<<8)     (offsets into packed 256-f LDS)
//         tcg[478]    : CG coefficient (f32)
__global__ void build_table(int* __restrict__ tiles, int* __restrict__ tpack,
                            float* __restrict__ tcg){
  const int tid = threadIdx.x;
  const int loff[4]   = {0,16,64,144};
  const int base[4]   = {0,1024,7936,22016};
  const int npairs[4] = {4,9,11,10};
  int tile_i = 0, term_i = 0;
  for (int l=0; l<=3; ++l){
    int pair_i = 0;
    for (int l1=0; l1<=3; ++l1){
      for (int l2=0; l2<=3; ++l2){
        if (!(abs(l1-l2)<=l && l<=l1+l2)) continue;
        for (int Mi=0; Mi<2*l+1; ++Mi){
          int M = Mi - l;
          int m1lo = max(-l1, M-l2), m1hi = min(l1, M+l2);
          int cnt = m1hi - m1lo + 1;
          int ooff = base[l] + (Mi*npairs[l] + pair_i)*256;
          if (tile_i == tid)
            tiles[tile_i] = ooff | (term_i<<16) | (cnt<<26);
          for (int m1=m1lo; m1<=m1hi; ++m1){
            if ((term_i & 255) == tid){
              int m2 = M - m1;
              int aoff = loff[l1] + (m1+l1)*16;
              int boff = loff[l2] + (m2+l2)*16;
              tpack[term_i] = aoff | (boff<<8);
              tcg[term_i]   = (float)cg_scalar(l1,m1,l2,m2,l,M);
            }
            term_i++;
          }
          tile_i++;
        }
        pair_i++;
      }
    }
  }
}

__global__ __launch_bounds__(256) void cg_main(
    const float* __restrict__ A0, const float* __restrict__ A1,
    const float* __restrict__ A2, const float* __restrict__ A3,
    const float* __restrict__ B0, const float* __restrict__ B1,
    const float* __restrict__ B2, const float* __restrict__ B3,
    const int* __restrict__ tiles, const int* __restrict__ tpack,
    const float* __restrict__ tcg, float* __restrict__ out)
{
  __shared__ __align__(16) float Ash[256];
  __shared__ __align__(16) float Bsh[256];
  __shared__ int   tiles_s[NTILES];
  __shared__ int   tpack_s[NTERMS];
  __shared__ float tcg_s[NTERMS];

  const int tid = threadIdx.x;
  const int b   = blockIdx.x;

  // stage packed A/B (256 floats each) into LDS
  {
    int pos = tid;
    float av, bv;
    if      (pos < 16)  { av = A0[b*16  + pos      ]; bv = B0[b*16  + pos      ]; }
    else if (pos < 64)  { av = A1[b*48  + pos - 16 ]; bv = B1[b*48  + pos - 16 ]; }
    else if (pos < 144) { av = A2[b*80  + pos - 64 ]; bv = B2[b*80  + pos - 64 ]; }
    else                { av = A3[b*112 + pos - 144]; bv = B3[b*112 + pos - 144]; }
    Ash[pos] = av; Bsh[pos] = bv;
  }
  if (tid < NTILES) tiles_s[tid] = tiles[tid];
  for (int i = tid; i < NTERMS; i += 256){ tpack_s[i] = tpack[i]; tcg_s[i] = tcg[i]; }
  __syncthreads();

  const int lane = tid & 63;
  const int wv   = tid >> 6;          // wave id 0..3 -> tile within group
  const int p    = lane >> 2;         // 0..15
  const int q0   = (lane & 3) * 4;    // 0,4,8,12
  float* outb = out + (size_t)b * PB_OUT;

  // 156 tiles, 4 waves -> 39 groups; each thread emits float4 per tile
  for (int tg = 0; tg < NTILES; tg += 4){
    int meta = tiles_s[tg + wv];
    int ooff = meta & 0xFFFF;
    int ts   = (meta >> 16) & 0x3FF;
    int tc   = meta >> 26;
    float4 acc = {0.f,0.f,0.f,0.f};
    for (int i = 0; i < tc; ++i){
      int   pk = tpack_s[ts + i];
      float cg = tcg_s[ts + i];
      float a  = Ash[(pk & 0xFF) + p];
      const float4 bq = *(const float4*)&Bsh[(pk >> 8) + q0];
      float ca = cg * a;
      acc.x = fmaf(ca, bq.x, acc.x);
      acc.y = fmaf(ca, bq.y, acc.y);
      acc.z = fmaf(ca, bq.z, acc.z);
      acc.w = fmaf(ca, bq.w, acc.w);
    }
    *(float4*)&outb[ooff + (lane << 2)] = acc;
  }
}

extern "C" void kernel_launch(void* const* d_in, const int* in_sizes, int n_in,
                              void* d_out, int out_size, void* d_ws, size_t ws_size,
                              hipStream_t stream)
{
  // setup_inputs() dict order is INTERLEAVED: A0,B0,A1,B1,A2,B2,A3,B3
  const float* A0 = (const float*)d_in[0];
  const float* B0 = (const float*)d_in[1];
  const float* A1 = (const float*)d_in[2];
  const float* B1 = (const float*)d_in[3];
  const float* A2 = (const float*)d_in[4];
  const float* B2 = (const float*)d_in[5];
  const float* A3 = (const float*)d_in[6];
  const float* B3 = (const float*)d_in[7];
  float* out = (float*)d_out;

  const int batch = in_sizes[0] / 16;   // A0 is [batch,1,16]

  char* ws    = (char*)d_ws;
  int*   tiles = (int*)(ws);            //  624 B
  int*   tpack = (int*)(ws + 1024);     // 1912 B
  float* tcg   = (float*)(ws + 4096);   // 1912 B  (total < 8 KB)

  build_table<<<1, 256, 0, stream>>>(tiles, tpack, tcg);
  cg_main<<<batch, 256, 0, stream>>>(A0,A1,A2,A3,B0,B1,B2,B3,
                                     tiles, tpack, tcg, out);
}